// Round 17
// baseline (277.149 us; speedup 1.0000x reference)
//
#include <hip/hip_runtime.h>

// Problem constants (fixed by the reference)
#define NN 200000   // nodes
#define CC 256      // channels
#define NG 512      // graphs/segments

typedef __attribute__((ext_vector_type(8))) __bf16 bf16x8;
typedef __attribute__((ext_vector_type(4))) float f32x4;

typedef unsigned short u16;

#define VWAITN(n) asm volatile("s_waitcnt vmcnt(%0)" :: "i"(n) : "memory")
#define LWAIT0()  asm volatile("s_waitcnt lgkmcnt(0)" ::: "memory")
#define SBAR() __builtin_amdgcn_s_barrier()

__device__ __forceinline__ u16 f2bf(float f) {
  union { float f; unsigned u; } v; v.f = f;
  unsigned u = v.u;
  u += 0x7fffu + ((u >> 16) & 1u);   // RNE
  return (u16)(u >> 16);
}
__device__ __forceinline__ unsigned pack2(float a, float b) {
  return (unsigned)f2bf(a) | ((unsigned)f2bf(b) << 16);
}
__device__ __forceinline__ float bflo(unsigned u){ union{unsigned u; float f;} x; x.u = u << 16; return x.f; }
__device__ __forceinline__ float bfhi(unsigned u){ union{unsigned u; float f;} x; x.u = u & 0xffff0000u; return x.f; }

// ---------------------------------------------------------------------------
// K0: prep weights into 16x16x32 MFMA A-operand fragment slices (16 KB each,
//  2 subtiles of 16 dims).  Slice order unchanged: 0..3 K-even, 4..7 Q-even,
//  8..11 K-odd, 12..15 Q-odd, 16..23 V, 24..31 Wo.
//  flat = s*8192 + sub*4096 + ks*512 + lane*8 + j  holds
//  W[k = ks*32 + (lane>>4)*8 + j][c0(s) + sub*16 + (lane&15)]
//  (A-frag mapping m89-verified: row=l&15, k=(l>>4)*8+j per 32-k step)
// ---------------------------------------------------------------------------
__global__ __launch_bounds__(256) void prep_kernel(
    const float* __restrict__ Wq, const float* __restrict__ Wk,
    const float* __restrict__ Wv, const float* __restrict__ Wo,
    u16* __restrict__ Wall) {
  int idx = blockIdx.x * 256 + threadIdx.x;     // 0..262143
  int s = idx >> 13;
  int r1 = idx & 8191;
  int sub = r1 >> 12;
  int r2 = r1 & 4095;
  int ks = r2 >> 9;
  int lane = (r2 >> 3) & 63;
  int j = r2 & 7;
  int k = ks * 32 + (lane >> 4) * 8 + j;
  const float* W; int c0;
  if (s < 16) {
    int p = s >> 3, r4 = s & 7;
    if (r4 < 4) { W = Wk; c0 = r4 * 64 + p * 32; }
    else        { W = Wq; c0 = (r4 - 4) * 64 + p * 32; }
  } else if (s < 24) { W = Wv; c0 = (s - 16) * 32; }
  else               { W = Wo; c0 = (s - 24) * 32; }
  Wall[idx] = f2bf(W[k * 256 + c0 + sub * 16 + (lane & 15)]);
}

// ---------------------------------------------------------------------------
// K1: segment boundaries from sorted batch.
// ---------------------------------------------------------------------------
__global__ __launch_bounds__(256) void seg_bounds_kernel(
    const int* __restrict__ batch, int* __restrict__ seg_start, int n) {
  int i = blockIdx.x * 256 + threadIdx.x;
  if (i >= n) return;
  int a = batch[i];
  int b = (i + 1 < n) ? batch[i + 1] : NG;
  for (int g = a + 1; g <= b; ++g) seg_start[g] = i + 1;
  if (i == 0) for (int g = 0; g <= a; ++g) seg_start[g] = 0;
}

// ---------------------------------------------------------------------------
// Stage a PAIR of consecutive 16 KB W slices (32 KB) into LDS:
// 8 waves x 4 reps x 64 lanes x 16 B.  vmcnt +4 per wave per call.
// ---------------------------------------------------------------------------
__device__ __forceinline__ void stage_pair(
    const u16* __restrict__ Wall, u16* dst_base, int s0, int t) {
#pragma unroll
  for (int rep = 0; rep < 4; ++rep) {
    int unit = rep * 512 + t;          // 0..2047
    const u16* src = Wall + (size_t)s0 * 8192 + unit * 8;
    u16* dst = dst_base + unit * 8;
    __builtin_amdgcn_global_load_lds(
        (const __attribute__((address_space(1))) void*)src,
        (__attribute__((address_space(3))) void*)dst, 16, 0, 0);
  }
}

// ---------------------------------------------------------------------------
// One 16(dims)x16(nodes) subtile over K=256: 8 MFMAs, A-frags from LDS
// (8 ds_read_b128), B (x) from registers (8 frags = 32 VGPR).
// ---------------------------------------------------------------------------
__device__ __forceinline__ f32x4 gemm16(
    const u16* buf, const bf16x8 xfr[8], int lane) {
  f32x4 acc = {0.f, 0.f, 0.f, 0.f};
#pragma unroll
  for (int ks = 0; ks < 8; ++ks) {
    bf16x8 af = *reinterpret_cast<const bf16x8*>(&buf[ks * 512 + lane * 8]);
    acc = __builtin_amdgcn_mfma_f32_16x16x32_bf16(af, xfr[ks], acc, 0, 0, 0);
  }
  return acc;
}

// ---------------------------------------------------------------------------
// K2: fused QKV + scores.  8 waves x 16 nodes = 128 nodes/block.
//  16x16 tiles halve per-wave state (xfr 32 + kph 16 + sp 16 + acc 4 ~ 110
//  regs) -> launch_bounds(512,4) pins <=128 -> 4 waves/SIMD residency.
//  Pair-steps, depth-1, counted vmcnt + raw s_barrier, biases in LDS,
//  tail index-clamped -> vmcnt-uniform blocks.
// ---------------------------------------------------------------------------
__global__ __launch_bounds__(512, 4) void qkv_scores_kernel(
    const float* __restrict__ x, const u16* __restrict__ Wall,
    const float* __restrict__ bq, const float* __restrict__ bk,
    const float* __restrict__ bv,
    u16* __restrict__ v_out,              // [NN][256] bf16
    float* __restrict__ scores) {         // [NN][16]
  __shared__ u16 Wbuf[2][16384];          // 2 x 32 KB pair buffers
  __shared__ float biasL[768];            // [bk | bq | bv]

  const int t = threadIdx.x;
  const int w = t >> 6, lane = t & 63;
  const int g4 = lane >> 4;               // dim-group 0..3
  int n = blockIdx.x * 128 + w * 16 + (lane & 15);
  if (n >= NN) n = NN - 1;                // clamp: duplicates write same values

  // ---- B-frags: x^T, 8 frags (32 VGPR). frag ks: k = ks*32 + g4*8 + j ----
  bf16x8 xfr[8];
#pragma unroll
  for (int ks = 0; ks < 8; ++ks) {
    const float* px = x + (size_t)n * CC + ks * 32 + g4 * 8;
    float4 a0 = *reinterpret_cast<const float4*>(px);
    float4 a1 = *reinterpret_cast<const float4*>(px + 4);
    uint4 u = {pack2(a0.x, a0.y), pack2(a0.z, a0.w),
               pack2(a1.x, a1.y), pack2(a1.z, a1.w)};
    xfr[ks] = *reinterpret_cast<bf16x8*>(&u);
  }
  // biases -> LDS (one-time; ds_read consumption, off the vm counter)
  biasL[t < 256 ? t : t] = 0.f;  // placate compiler ordering (overwritten below)
  if (t < 256) { biasL[t] = bk[t]; biasL[512 + t] = bv[t]; }
  else         { biasL[t] = bq[t - 256]; }

  stage_pair(Wall, Wbuf[0], 0, t);        // pair = slices 0,1
  LWAIT0();                               // bias LDS writes done pre-barrier

  float sp[16];
#pragma unroll
  for (int i = 0; i < 16; ++i) sp[i] = 0.f;

  int bi = 0;

  // ---- K/Q phases: 8 pair-steps over slices 0..15 ----
#pragma unroll 1
  for (int p = 0; p < 2; ++p) {
    unsigned kph[4][4];          // k packed bf16: [head][sub*2 + r/2]
#pragma unroll
    for (int pr = 0; pr < 2; ++pr) {      // K pair: heads 2pr, 2pr+1
      const int s0 = p * 8 + pr * 2;
      VWAITN(0);
      SBAR();
      stage_pair(Wall, Wbuf[bi ^ 1], s0 + 2, t);
#pragma unroll
      for (int so = 0; so < 2; ++so) {    // slice offset (head)
        const int g = pr * 2 + so;
#pragma unroll
        for (int sub = 0; sub < 2; ++sub) {
          f32x4 acc = gemm16(&Wbuf[bi][so * 8192 + sub * 4096], xfr, lane);
          float4 b4 = *reinterpret_cast<const float4*>(
              &biasL[g * 64 + p * 32 + sub * 16 + g4 * 4]);
          kph[g][sub * 2]     = pack2(acc[0] + b4.x, acc[1] + b4.y);
          kph[g][sub * 2 + 1] = pack2(acc[2] + b4.z, acc[3] + b4.w);
        }
      }
      bi ^= 1;
    }
#pragma unroll
    for (int pr = 0; pr < 2; ++pr) {      // Q pair: heads 2pr, 2pr+1
      const int s0 = p * 8 + 4 + pr * 2;
      VWAITN(0);
      SBAR();
      stage_pair(Wall, Wbuf[bi ^ 1], s0 + 2, t);   // s0+2 <= 16 (first V)
#pragma unroll
      for (int so = 0; so < 2; ++so) {
        const int h = pr * 2 + so;
#pragma unroll
        for (int sub = 0; sub < 2; ++sub) {
          f32x4 acc = gemm16(&Wbuf[bi][so * 8192 + sub * 4096], xfr, lane);
          float4 b4 = *reinterpret_cast<const float4*>(
              &biasL[256 + h * 64 + p * 32 + sub * 16 + g4 * 4]);
          float qv[4] = {acc[0] + b4.x, acc[1] + b4.y,
                         acc[2] + b4.z, acc[3] + b4.w};
#pragma unroll
          for (int r = 0; r < 4; ++r) {
#pragma unroll
            for (int g = 0; g < 4; ++g) {
              unsigned kk = kph[g][sub * 2 + (r >> 1)];
              float kv = (r & 1) ? bfhi(kk) : bflo(kk);
              sp[h * 4 + g] += qv[r] * kv;
            }
          }
        }
      }
      bi ^= 1;
    }
  }

  // ---- scores: reduce over dim-groups (lanes 16k) + store (lane<16) ----
#pragma unroll
  for (int i = 0; i < 16; ++i) {
    sp[i] += __shfl_xor(sp[i], 16, 64);
    sp[i] += __shfl_xor(sp[i], 32, 64);
  }
  if (lane < 16) {
#pragma unroll
    for (int q = 0; q < 4; ++q) {
      float4 o = {sp[q * 4] * 0.125f, sp[q * 4 + 1] * 0.125f,
                  sp[q * 4 + 2] * 0.125f, sp[q * 4 + 3] * 0.125f};
      *reinterpret_cast<float4*>(scores + (size_t)n * 16 + q * 4) = o;
    }
  }

  // ---- V phase: 4 pair-steps over slices 16..23 ----
#pragma unroll
  for (int i = 0; i < 4; ++i) {
    const int s0 = 16 + 2 * i;
    VWAITN(4);   // retire stage(s0); 4 newer stores (scores or prev V) stay
    SBAR();
    if (i < 3) stage_pair(Wall, Wbuf[bi ^ 1], s0 + 2, t);
#pragma unroll
    for (int so = 0; so < 2; ++so) {
      const int sv = 2 * i + so;
#pragma unroll
      for (int sub = 0; sub < 2; ++sub) {
        f32x4 acc = gemm16(&Wbuf[bi][so * 8192 + sub * 4096], xfr, lane);
        int d0 = sv * 32 + sub * 16 + g4 * 4;
        float4 b4 = *reinterpret_cast<const float4*>(&biasL[512 + d0]);
        uint2 pk = {pack2(acc[0] + b4.x, acc[1] + b4.y),
                    pack2(acc[2] + b4.z, acc[3] + b4.w)};
        *reinterpret_cast<uint2*>(v_out + (size_t)n * CC + d0) = pk;
      }
    }
    bi ^= 1;
  }
}

// ---------------------------------------------------------------------------
// K3: per-segment max & exp-sum over the 16 score columns (block per segment).
// ---------------------------------------------------------------------------
__global__ __launch_bounds__(256) void seg_softmax_kernel(
    const float* __restrict__ scores, const int* __restrict__ seg_start,
    float* __restrict__ seg_max, float* __restrict__ seg_sum) {
  __shared__ float red[256];
  int g = blockIdx.x;
  int s = seg_start[g], e = seg_start[g + 1];
  int t = threadIdx.x;
  int col = t & 15, sub = t >> 4;

  float m = -INFINITY;
  for (int i = s + sub; i < e; i += 16)
    m = fmaxf(m, scores[(size_t)i * 16 + col]);
  red[t] = m;
  __syncthreads();
  for (int step = 8; step >= 1; step >>= 1) {
    if (sub < step) red[t] = fmaxf(red[t], red[t + step * 16]);
    __syncthreads();
  }
  if (t < 16) seg_max[g * 16 + t] = red[t];
  float mcol = red[col];
  __syncthreads();

  float sum = 0.f;
  for (int i = s + sub; i < e; i += 16)
    sum += expf(scores[(size_t)i * 16 + col] - mcol);
  red[t] = sum;
  __syncthreads();
  for (int step = 8; step >= 1; step >>= 1) {
    if (sub < step) red[t] += red[t + step * 16];
    __syncthreads();
  }
  if (t < 16) seg_sum[g * 16 + t] = red[t];
}

// ---------------------------------------------------------------------------
// K4: fused att + att.v + output GEMM (+bo) + att_mean.  8 waves x 16 nodes;
//  16x16 tiles; 4 pair-steps over Wo slices 24..31; bo in LDS; clamped tail.
// ---------------------------------------------------------------------------
__global__ __launch_bounds__(512, 4) void out_kernel(
    const u16* __restrict__ v_bf, const float* __restrict__ scores,
    const int* __restrict__ batch, const float* __restrict__ seg_max,
    const float* __restrict__ seg_sum, const u16* __restrict__ Wall,
    const float* __restrict__ bo, float* __restrict__ out,
    float* __restrict__ att_mean) {
  __shared__ u16 Wbuf[2][16384];
  __shared__ float boL[256];

  const int t = threadIdx.x;
  const int w = t >> 6, lane = t & 63;
  const int g4 = lane >> 4;
  int n = blockIdx.x * 128 + w * 16 + (lane & 15);
  if (n >= NN) n = NN - 1;                // clamp: duplicates write same values

  // ---- att[16] for this lane's node ----
  int b = batch[n];
  float att[16];
#pragma unroll
  for (int q = 0; q < 4; ++q) {
    float4 sc = *reinterpret_cast<const float4*>(scores + (size_t)n * 16 + q * 4);
    float4 mx = *reinterpret_cast<const float4*>(seg_max + b * 16 + q * 4);
    float4 sm = *reinterpret_cast<const float4*>(seg_sum + b * 16 + q * 4);
    att[q * 4 + 0] = expf(sc.x - mx.x) / (sm.x + 1e-16f);
    att[q * 4 + 1] = expf(sc.y - mx.y) / (sm.y + 1e-16f);
    att[q * 4 + 2] = expf(sc.z - mx.z) / (sm.z + 1e-16f);
    att[q * 4 + 3] = expf(sc.w - mx.w) / (sm.w + 1e-16f);
  }

  if (t < 256) boL[t] = bo[t];

  // att_mean (lane<16; 1 masked store, older than stage -> retires early)
  if (lane < 16) {
    float4 am;
    am.x = 0.25f * (att[0] + att[4] + att[8] + att[12]);
    am.y = 0.25f * (att[1] + att[5] + att[9] + att[13]);
    am.z = 0.25f * (att[2] + att[6] + att[10] + att[14]);
    am.w = 0.25f * (att[3] + att[7] + att[11] + att[15]);
    *reinterpret_cast<float4*>(att_mean + (size_t)n * 4) = am;
  }

  // ---- v loads: 8 x uint4 (per g, per parity half) ----
  uint4 vv[4][2];
#pragma unroll
  for (int g = 0; g < 4; ++g)
#pragma unroll
    for (int par = 0; par < 2; ++par)
      vv[g][par] = *reinterpret_cast<const uint4*>(
          v_bf + (size_t)n * CC + g * 64 + par * 32 + g4 * 8);

  stage_pair(Wall, Wbuf[0], 24, t);

  // ---- oaf B-frags: frag ks covers k = ks*32 + g4*8 + j ----
  // k = h*64 + dd -> h = ks>>1, dd = (ks&1)*32 + g4*8 + j
  bf16x8 oaf[8];
#pragma unroll
  for (int ks = 0; ks < 8; ++ks) {
    const int h = ks >> 1, par = ks & 1;
    unsigned res[4];
#pragma unroll
    for (int jj = 0; jj < 4; ++jj) {
      unsigned u0 = ((const unsigned*)&vv[0][par])[jj];
      unsigned u1 = ((const unsigned*)&vv[1][par])[jj];
      unsigned u2 = ((const unsigned*)&vv[2][par])[jj];
      unsigned u3 = ((const unsigned*)&vv[3][par])[jj];
      float lo = att[h * 4 + 0] * bflo(u0) + att[h * 4 + 1] * bflo(u1) +
                 att[h * 4 + 2] * bflo(u2) + att[h * 4 + 3] * bflo(u3);
      float hf = att[h * 4 + 0] * bfhi(u0) + att[h * 4 + 1] * bfhi(u1) +
                 att[h * 4 + 2] * bfhi(u2) + att[h * 4 + 3] * bfhi(u3);
      res[jj] = pack2(lo, hf);
    }
    uint4 u = {res[0], res[1], res[2], res[3]};
    oaf[ks] = *reinterpret_cast<bf16x8*>(&u);
  }
  LWAIT0();                               // boL visible pre-barrier

  // ---- output GEMM: 4 pair-steps over Wo slices 24..31 ----
  int bi = 0;
#pragma unroll
  for (int i = 0; i < 4; ++i) {
    if (i == 0) { VWAITN(0); }   // pair(24,25) landed (v/att loads retire too)
    else        { VWAITN(4); }   // retire pair stage; 4 out-stores in flight
    SBAR();
    if (i < 3) stage_pair(Wall, Wbuf[bi ^ 1], 26 + 2 * i, t);
#pragma unroll
    for (int so = 0; so < 2; ++so) {
      const int sl = 2 * i + so;           // Wo slice rel 0..7
#pragma unroll
      for (int sub = 0; sub < 2; ++sub) {
        f32x4 acc = gemm16(&Wbuf[bi][so * 8192 + sub * 4096], oaf, lane);
        int c0 = sl * 32 + sub * 16 + g4 * 4;
        float4 b4 = *reinterpret_cast<const float4*>(&boL[c0]);
        float4 o = {acc[0] + b4.x, acc[1] + b4.y,
                    acc[2] + b4.z, acc[3] + b4.w};
        *reinterpret_cast<float4*>(out + (size_t)n * CC + c0) = o;
      }
    }
    bi ^= 1;
  }
}

// ---------------------------------------------------------------------------
extern "C" void kernel_launch(void* const* d_in, const int* in_sizes, int n_in,
                              void* d_out, int out_size, void* d_ws, size_t ws_size,
                              hipStream_t stream) {
  const float* x  = (const float*)d_in[0];
  const int* batch = (const int*)d_in[1];
  const float* Wq = (const float*)d_in[2];
  const float* bq = (const float*)d_in[3];
  const float* Wk = (const float*)d_in[4];
  const float* bk = (const float*)d_in[5];
  const float* Wv = (const float*)d_in[6];
  const float* bv = (const float*)d_in[7];
  const float* Wo = (const float*)d_in[8];
  const float* bo = (const float*)d_in[9];

  char* ws = (char*)d_ws;
  u16*   Wall      = (u16*)ws;                               //   524,288 B (32 slices)
  int*   seg_start = (int*)(ws + 524288);                    //     2,052 B
  float* seg_max   = (float*)(ws + 528384);                  //    32,768 B
  float* seg_sum   = (float*)(ws + 561152);                  //    32,768 B
  float* scores    = (float*)(ws + 593920);                  // 12,800,000 B
  u16*   v_bf      = (u16*)(ws + 13393920);                  // 102,400,000 B

  float* out = (float*)d_out;
  float* att_mean = out + (size_t)NN * CC;

  const int NB = (NN + 127) / 128;   // 1563 blocks of 128 nodes

  prep_kernel<<<1024, 256, 0, stream>>>(Wq, Wk, Wv, Wo, Wall);
  seg_bounds_kernel<<<(NN + 255) / 256, 256, 0, stream>>>(batch, seg_start, NN);
  qkv_scores_kernel<<<NB, 512, 0, stream>>>(x, Wall, bq, bk, bv, v_bf, scores);
  seg_softmax_kernel<<<NG, 256, 0, stream>>>(scores, seg_start, seg_max, seg_sum);
  out_kernel<<<NB, 512, 0, stream>>>(v_bf, scores, batch, seg_max, seg_sum,
                                     Wall, bo, out, att_mean);
}